// Round 11
// baseline (1294.204 us; speedup 1.0000x reference)
//
#include <hip/hip_runtime.h>
#include <hip/hip_cooperative_groups.h>
#include <math.h>

namespace cg = cooperative_groups;

#define NEG_SLOPE 0.2f
#define EPSV 1e-16f
#define NEG_HUGE -1e30f
#define CAP 64    // slots per node; deg ~ Poisson(16)+1, P(deg>63) ~ 1e-12
#define GH  512   // legacy fused builder blocks (64 stripes x 8 classes)
#define GB1 1024  // coop builder blocks (128 stripes x 8 classes)
#define GRID_COOP 1792   // 7 blocks/CU x 256 CUs; launch_bounds(256,7) guarantees residency

typedef short short8 __attribute__((ext_vector_type(8)));   // 8 bf16 (4 VGPRs)
typedef float f32x4 __attribute__((ext_vector_type(4)));
typedef unsigned short u16;

// cnt layout CLASS-MAJOR: cnt[(d&7)*NP + (d>>3)], NP padded to 32 ints.
// R3: no per-row matvec fusion. R6: no NT loads/stores. R7: hist not
// fetch-bound. R9: bf16 xl halves gather traffic (verified) but total flat.
// R10: 8-deep gather MLP flat -> attn not depth-bound.
// R11: R8 vs R10 delta shows a dispatch boundary costs ~10-15us; 4 boundaries
// ~= 40-60us. Collapse to ONE cooperative kernel with grid.sync() phase
// barriers (guide-sanctioned; harness supports hipLaunchCooperativeKernel).
// Kernel bodies are R10-proven, unchanged. Fallback to the 5-dispatch path
// if the cooperative launch errors.

__device__ __forceinline__ u16 f2bf(float f) {            // RNE fp32->bf16
    const unsigned u = __float_as_uint(f);
    return (u16)((u + 0x7fffu + ((u >> 16) & 1u)) >> 16);
}
__device__ __forceinline__ float bf2f(u16 h) {
    return __uint_as_float(((unsigned)h) << 16);
}

// ---------------- split fp32 x8 -> bf16 hi/lo -------------------------------
__device__ __forceinline__ void split8(const float* fs, short8& ahi, short8& alo) {
#pragma unroll
    for (int j = 0; j < 8; ++j) {
        const unsigned u = __float_as_uint(fs[j]);
        ahi[j] = (short)(u >> 16);
        const float hif = __uint_as_float(u & 0xffff0000u);
        alo[j] = (short)(__float_as_uint(fs[j] - hif) >> 16);
    }
}

// ---------------- W pack + cnt/csrc prefill body ----------------------------
__device__ __forceinline__ void wpack_body(
        const float* __restrict__ W1l, const float* __restrict__ W1r,
        const float* __restrict__ W2l, const float* __restrict__ W2r,
        u16* __restrict__ w1hi, u16* __restrict__ w1lo,
        u16* __restrict__ w2hi, u16* __restrict__ w2lo,
        int* __restrict__ cnt, u16* __restrict__ csrc,
        int N, int NP, int idx, int G) {
    const int CN = 8 * NP;
    for (int i = idx; i < CN; i += G) {
        const int cls = i / NP;
        const int r = i - cls * NP;
        const int d = r * 8 + cls;
        cnt[i] = (d < N) ? 1 : 0;         // slot 0 pre-reserved for self loop
    }
    for (int d = idx; d < N; d += G) csrc[(size_t)d * CAP] = (u16)d;
    const int T1 = 128 * 128, T2 = 64 * 128;
    for (int li0 = idx; li0 < T1 + T2; li0 += G) {
        u16 *dhi, *dlo; const float *Wl, *Wr; int li;
        if (li0 < T1) { dhi = w1hi; dlo = w1lo; Wl = W1l; Wr = W1r; li = li0; }
        else          { dhi = w2hi; dlo = w2lo; Wl = W2l; Wr = W2r; li = li0 - T1; }
        const int j = li & 7, l = (li >> 3) & 63, t = (li >> 9) & 7, c = li >> 12;
        const int k = c * 32 + (l >> 4) * 8 + j;
        const int n = t * 16 + (l & 15);
        const float v = (n < 64) ? Wl[k * 64 + n] : Wr[k * 64 + (n - 64)];
        const unsigned u = __float_as_uint(v);
        dhi[li] = (u16)(u >> 16);
        const float hif = __uint_as_float(u & 0xffff0000u);
        dlo[li] = (u16)(__float_as_uint(v - hif) >> 16);
    }
}

// ---------------- CSR build body (XCD-class partitioned, R4-proven) ---------
__device__ __forceinline__ void build_body(const int* __restrict__ ei, int E,
                                           int* __restrict__ cnt,
                                           u16* __restrict__ csrc,
                                           int NP, int cls, int stripe, int NS,
                                           int tid) {
    const int* srcp = ei;
    const int* dstp = ei + E;
    int* cntc = cnt + cls * NP;
    if ((E & 3) == 0) {
        for (int base = stripe * 1024; base < E; base += NS * 1024) {
            const int e4 = base + tid * 4;
            if (e4 < E) {   // E%4==0 -> e4+3 <= E-1
                const int4 d4 = *(const int4*)(dstp + e4);
                const int4 s4 = *(const int4*)(srcp + e4);
                const int d[4] = {d4.x, d4.y, d4.z, d4.w};
                const int s[4] = {s4.x, s4.y, s4.z, s4.w};
                bool m[4]; int sl[4];
#pragma unroll
                for (int j = 0; j < 4; ++j) {
                    m[j] = (d[j] & 7) == cls;
                    if (m[j]) sl[j] = atomicAdd(&cntc[d[j] >> 3], 1);
                }
#pragma unroll
                for (int j = 0; j < 4; ++j) {
                    if (m[j]) csrc[(size_t)d[j] * CAP + sl[j]] = (u16)s[j];
                }
            }
        }
    } else {
        for (int base = stripe * 256; base < E; base += NS * 256) {
            const int e = base + tid;
            if (e < E) {
                const int dd = dstp[e];
                if ((dd & 7) == cls) {
                    const int ss = srcp[e];
                    const int slot = atomicAdd(&cntc[dd >> 3], 1);
                    csrc[(size_t)dd * CAP + slot] = (u16)ss;
                }
            }
        }
    }
}

// ---------------- split-bf16 MFMA GEMM tile (no LDS, R10-proven) ------------
// Operands swapped: mfma(Wfrag, Xfrag) computes Y^T in fragment space ->
// lane l, reg r holds Y[rowbase+(l&15)][t*16+(l>>4)*4+r]: one vector store
// per tile. xl (attn gather source) written bf16; xr fp32.
// D = Whi*Xhi + Wlo*Xhi + Whi*Xlo (lo*lo dropped, ~2^-16 rel).
template <int K>
__device__ __forceinline__ void gemm_mfma_tile(const float* __restrict__ X,
                                               const u16* __restrict__ whi,
                                               const u16* __restrict__ wlo,
                                               u16* __restrict__ xl,
                                               float* __restrict__ xr,
                                               int N, int tile, int tid) {
    const int lane = tid & 63;
    const int w = tid >> 6;
    const int rowbase = tile * 64 + w * 16;
    const int m = lane & 15, q = lane >> 4;
    int ar = rowbase + m; if (ar > N - 1) ar = N - 1;       // clamped read, masked write
    const float* arow = X + (size_t)ar * K + q * 8;
    f32x4 acc[8];
#pragma unroll
    for (int t = 0; t < 8; ++t) acc[t] = (f32x4){0.f, 0.f, 0.f, 0.f};
#pragma unroll
    for (int c = 0; c < K / 32; ++c) {
        const float4 f0 = *(const float4*)(arow + c * 32);
        const float4 f1 = *(const float4*)(arow + c * 32 + 4);
        const float fs[8] = {f0.x, f0.y, f0.z, f0.w, f1.x, f1.y, f1.z, f1.w};
        short8 ahi, alo;
        split8(fs, ahi, alo);
        const u16* bp = whi + ((size_t)(c * 8) * 64 + lane) * 8;
        const u16* bq = wlo + ((size_t)(c * 8) * 64 + lane) * 8;
#pragma unroll
        for (int t = 0; t < 8; ++t) {
            const short8 bhi = *(const short8*)(bp + t * 64 * 8);
            const short8 blo = *(const short8*)(bq + t * 64 * 8);
            acc[t] = __builtin_amdgcn_mfma_f32_16x16x32_bf16(bhi, ahi, acc[t], 0, 0, 0);
            acc[t] = __builtin_amdgcn_mfma_f32_16x16x32_bf16(blo, ahi, acc[t], 0, 0, 0);
            acc[t] = __builtin_amdgcn_mfma_f32_16x16x32_bf16(bhi, alo, acc[t], 0, 0, 0);
        }
    }
    const int row = rowbase + m;
    if (row < N) {
#pragma unroll
        for (int t = 0; t < 8; ++t) {
            const int colb = t * 16 + q * 4;
            if (t < 4) {
                ushort4 hv;
                hv.x = f2bf(acc[t][0]); hv.y = f2bf(acc[t][1]);
                hv.z = f2bf(acc[t][2]); hv.w = f2bf(acc[t][3]);
                *(ushort4*)(xl + (size_t)row * 64 + colb) = hv;   // 8B store
            } else {
                float4 v;
                v.x = acc[t][0]; v.y = acc[t][1]; v.z = acc[t][2]; v.w = acc[t][3];
                *(float4*)(xr + (size_t)row * 64 + (colb - 64)) = v;
            }
        }
    }
}

// ---------------- attn core: NT*16 edge slots, all gathers issued first -----
template <int NT>
__device__ __forceinline__ void attn_core(const u16* __restrict__ xl,
                                          int sidx, int deg, int base,
                                          int g, int i,
                                          const float4 xrv, const float4 aw,
                                          float& l, float4& acc) {
    ushort4 u[NT][4];
    bool vv[NT][4];
#pragma unroll
    for (int nt = 0; nt < NT; ++nt) {
#pragma unroll
        for (int j = 0; j < 4; ++j) {
            const int s = base + nt * 16 + j * 4 + g;
            vv[nt][j] = s < deg;
            const int src = __shfl(sidx, s, 64);
            u[nt][j] = *(const ushort4*)(xl + (size_t)src * 64 + i * 4);
        }
    }
#pragma unroll
    for (int nt = 0; nt < NT; ++nt) {
#pragma unroll
        for (int j = 0; j < 4; ++j) {
            float4 va;
            va.x = bf2f(u[nt][j].x); va.y = bf2f(u[nt][j].y);
            va.z = bf2f(u[nt][j].z); va.w = bf2f(u[nt][j].w);
            float t0, pp;
            t0 = va.x + xrv.x; t0 = fmaxf(t0, NEG_SLOPE * t0); pp = aw.x * t0;
            t0 = va.y + xrv.y; t0 = fmaxf(t0, NEG_SLOPE * t0); pp = fmaf(aw.y, t0, pp);
            t0 = va.z + xrv.z; t0 = fmaxf(t0, NEG_SLOPE * t0); pp = fmaf(aw.z, t0, pp);
            t0 = va.w + xrv.w; t0 = fmaxf(t0, NEG_SLOPE * t0); pp = fmaf(aw.w, t0, pp);
            pp += __shfl_xor(pp, 1, 64);
            pp += __shfl_xor(pp, 2, 64);
            pp += __shfl_xor(pp, 4, 64);
            pp += __shfl_xor(pp, 8, 64);
            const float dj = __expf(vv[nt][j] ? pp : NEG_HUGE);
            l += dj;
            acc.x = fmaf(dj, va.x, acc.x);
            acc.y = fmaf(dj, va.y, acc.y);
            acc.z = fmaf(dj, va.z, acc.z);
            acc.w = fmaf(dj, va.w, acc.w);
        }
    }
}

// ---------------- attn body (one wave per dst; deg wave-uniform) ------------
// xr/out may alias (layer 2: per-wave row read-then-write only).
__device__ __forceinline__ void attn_body(const u16* __restrict__ xl,
                                          const float* xr,
                                          const float* __restrict__ att,
                                          const int* __restrict__ cnt,
                                          const u16* __restrict__ csrc,
                                          const float* __restrict__ bias,
                                          float* out, int N, int NP, int relu,
                                          int vb, int tid) {
    const int lane = tid & 63;
    const int g = lane >> 4;
    const int i = lane & 15;
    const int dst = vb * 4 + (tid >> 6);
    if (dst >= N) return;    // function-level return: caller still reaches sync
    const float4 xrv = *(const float4*)(xr + (size_t)dst * 64 + i * 4);
    const float4 aw  = *(const float4*)(att + i * 4);
    const int deg = cnt[(dst & 7) * NP + (dst >> 3)];
    const int sidx = (int)csrc[(size_t)dst * CAP + ((lane < deg) ? lane : 0)];
    float l = 0.0f;
    float4 acc = {0.0f, 0.0f, 0.0f, 0.0f};
    if (deg <= 16) {
        attn_core<1>(xl, sidx, deg, 0, g, i, xrv, aw, l, acc);
    } else if (deg <= 32) {
        attn_core<2>(xl, sidx, deg, 0, g, i, xrv, aw, l, acc);
    } else {          // 0.03% of waves
        attn_core<2>(xl, sidx, deg, 0, g, i, xrv, aw, l, acc);
        attn_core<2>(xl, sidx, deg, 32, g, i, xrv, aw, l, acc);
    }
#pragma unroll
    for (int o = 16; o <= 32; o <<= 1) {
        l     += __shfl_xor(l, o, 64);
        acc.x += __shfl_xor(acc.x, o, 64);
        acc.y += __shfl_xor(acc.y, o, 64);
        acc.z += __shfl_xor(acc.z, o, 64);
        acc.w += __shfl_xor(acc.w, o, 64);
    }
    if (g == 0) {
        const float4 bv = *(const float4*)(bias + i * 4);
        const float inv = 1.0f / (l + EPSV);
        float4 r;
        r.x = fmaf(acc.x, inv, bv.x);
        r.y = fmaf(acc.y, inv, bv.y);
        r.z = fmaf(acc.z, inv, bv.z);
        r.w = fmaf(acc.w, inv, bv.w);
        if (relu) {
            r.x = fmaxf(r.x, 0.0f); r.y = fmaxf(r.y, 0.0f);
            r.z = fmaxf(r.z, 0.0f); r.w = fmaxf(r.w, 0.0f);
        }
        *(float4*)(out + (size_t)dst * 64 + i * 4) = r;
    }
}

// ---------------- THE cooperative mega-kernel (one dispatch, 5 phases) ------
__global__ __launch_bounds__(256, 7) void k_fused(
        const float* x, const int* ei, int E,
        const float* W1l, const float* W1r, const float* W2l, const float* W2r,
        const float* att1, const float* b1, const float* att2, const float* b2,
        int* cnt, u16* csrc, u16* w1hi, u16* w1lo, u16* w2hi, u16* w2lo,
        float* buf1, float* buf2, float* fout, int N, int NP) {
    cg::grid_group grid = cg::this_grid();
    const int tid = threadIdx.x;
    const int bid = blockIdx.x;
    const int nb  = gridDim.x;
    const int idx = bid * 256 + tid;
    const int G   = nb * 256;
    const int nT  = (N + 63) >> 6;     // 64-row tiles (both gemms)
    const int gA  = (N + 3) >> 2;      // attn virtual blocks (4 dst each)

    // phase 0: W packs + cnt init + csrc self-loop prefill
    wpack_body(W1l, W1r, W2l, W2r, w1hi, w1lo, w2hi, w2lo, cnt, csrc, N, NP, idx, G);
    grid.sync();

    // phase 1: CSR build (blocks 0..GB1) || layer-1 gemm (rest, grid-stride)
    if (bid < GB1) {
        build_body(ei, E, cnt, csrc, NP, bid & 7, bid >> 3, GB1 >> 3, tid);
    } else {
        for (int t = bid - GB1; t < nT; t += nb - GB1)
            gemm_mfma_tile<128>(x, w1hi, w1lo, (u16*)fout, buf1, N, t, tid);
    }
    grid.sync();

    // phase 2: layer-1 attention (xl1 bf16 in fout, xr1 in buf1) -> h in buf2
    for (int vb = bid; vb < gA; vb += nb)
        attn_body((const u16*)fout, buf1, att1, cnt, csrc, b1, buf2, N, NP, 1, vb, tid);
    grid.sync();

    // phase 3: layer-2 gemm (h in buf2) -> xl2 bf16 in buf1, xr2 f32 in fout
    for (int t = bid; t < nT; t += nb)
        gemm_mfma_tile<64>(buf2, w2hi, w2lo, (u16*)buf1, fout, N, t, tid);
    grid.sync();

    // phase 4: layer-2 attention -> final out (fout; per-wave row r-then-w)
    for (int vb = bid; vb < gA; vb += nb)
        attn_body((const u16*)buf1, fout, att2, cnt, csrc, b2, fout, N, NP, 0, vb, tid);
}

// ---------------- legacy 5-dispatch path (R10-exact; fallback) --------------
__global__ __launch_bounds__(256) void k_wpack(
        const float* __restrict__ W1l, const float* __restrict__ W1r,
        const float* __restrict__ W2l, const float* __restrict__ W2r,
        u16* __restrict__ w1hi, u16* __restrict__ w1lo,
        u16* __restrict__ w2hi, u16* __restrict__ w2lo,
        int* __restrict__ cnt, u16* __restrict__ csrc, int N, int NP) {
    wpack_body(W1l, W1r, W2l, W2r, w1hi, w1lo, w2hi, w2lo, cnt, csrc, N, NP,
               blockIdx.x * 256 + threadIdx.x, gridDim.x * 256);
}

template <int K>
__global__ __launch_bounds__(256) void k_hist_gemm(const int* __restrict__ ei, int E,
                                                   int* __restrict__ cnt,
                                                   u16* __restrict__ csrc,
                                                   const float* __restrict__ X,
                                                   const u16* __restrict__ whi,
                                                   const u16* __restrict__ wlo,
                                                   u16* __restrict__ xl,
                                                   float* __restrict__ xr,
                                                   int N, int NP) {
    if ((int)blockIdx.x < GH) {
        build_body(ei, E, cnt, csrc, NP, blockIdx.x & 7, blockIdx.x >> 3, GH >> 3,
                   threadIdx.x);
    } else {
        gemm_mfma_tile<K>(X, whi, wlo, xl, xr, N, blockIdx.x - GH, threadIdx.x);
    }
}

template <int K>
__global__ __launch_bounds__(256) void k_gemm(const float* __restrict__ X,
                                              const u16* __restrict__ whi,
                                              const u16* __restrict__ wlo,
                                              u16* __restrict__ xl,
                                              float* __restrict__ xr, int N) {
    gemm_mfma_tile<K>(X, whi, wlo, xl, xr, N, blockIdx.x, threadIdx.x);
}

__global__ __launch_bounds__(256) void k_attn(const u16* __restrict__ xl,
                                              const float* xr,
                                              const float* __restrict__ att,
                                              const int* __restrict__ cnt,
                                              const u16* __restrict__ csrc,
                                              const float* __restrict__ bias,
                                              float* out, int N, int NP, int relu) {
    attn_body(xl, xr, att, cnt, csrc, bias, out, N, NP, relu, blockIdx.x, threadIdx.x);
}

// ---------------- launch ----------------

extern "C" void kernel_launch(void* const* d_in, const int* in_sizes, int n_in,
                              void* d_out, int out_size, void* d_ws, size_t ws_size,
                              hipStream_t stream) {
    const float* x    = (const float*)d_in[0];
    const int*   ei   = (const int*)d_in[1];
    const float* W1l  = (const float*)d_in[2];
    const float* W1r  = (const float*)d_in[3];
    const float* att1 = (const float*)d_in[4];
    const float* b1   = (const float*)d_in[5];
    const float* W2l  = (const float*)d_in[6];
    const float* W2r  = (const float*)d_in[7];
    const float* att2 = (const float*)d_in[8];
    const float* b2   = (const float*)d_in[9];

    int N  = in_sizes[0] / 128;
    int E  = in_sizes[1] / 2;
    int NP = (((N + 7) >> 3) + 31) & ~31;   // per-class cnt stride, 128B-aligned

    // ws: cnt(8*NP) | csrc(u16) | W packs | buf1 | buf2
    int* wsi   = (int*)d_ws;
    int* cnt   = wsi;                        // 8*NP ints (class-major)
    u16* csrc  = (u16*)(cnt + 8 * NP);       // N*CAP u16
    u16* w1hi  = csrc + (size_t)N * CAP;
    u16* w1lo  = w1hi + 16384;
    u16* w2hi  = w1lo + 16384;
    u16* w2lo  = w2hi + 8192;
    float* buf1 = (float*)(w2lo + 8192);     // N*64 f32 (xr1), then N*64 bf16 (xl2)
    float* buf2 = buf1 + (size_t)N * 64;     // N*64 f32 (h)
    float* fout = (float*)d_out;             // xl1 (bf16), then xr2, then final out

    // ---- try the single cooperative dispatch ----
    void* args[] = {
        (void*)&x, (void*)&ei, (void*)&E,
        (void*)&W1l, (void*)&W1r, (void*)&W2l, (void*)&W2r,
        (void*)&att1, (void*)&b1, (void*)&att2, (void*)&b2,
        (void*)&cnt, (void*)&csrc, (void*)&w1hi, (void*)&w1lo,
        (void*)&w2hi, (void*)&w2lo,
        (void*)&buf1, (void*)&buf2, (void*)&fout, (void*)&N, (void*)&NP,
    };
    hipError_t err = hipLaunchCooperativeKernel((const void*)k_fused,
                                                dim3(GRID_COOP), dim3(256),
                                                args, 0, stream);
    if (err == hipSuccess) return;

    // ---- fallback: R10-exact 5-dispatch path ----
    const dim3 b256(256);
    const int gGemm = (N + 63) / 64;
    const int gAttn = (N + 3) / 4;

    k_wpack<<<96, b256, 0, stream>>>(
        W1l, W1r, W2l, W2r, w1hi, w1lo, w2hi, w2lo, cnt, csrc, N, NP);
    k_hist_gemm<128><<<GH + gGemm, b256, 0, stream>>>(ei, E, cnt, csrc,
                                                      x, w1hi, w1lo,
                                                      (u16*)fout, buf1, N, NP);
    k_attn<<<gAttn, b256, 0, stream>>>((const u16*)fout, buf1, att1, cnt, csrc, b1,
                                       buf2, N, NP, 1);
    k_gemm<64><<<gGemm, b256, 0, stream>>>(buf2, w2hi, w2lo, (u16*)buf1, fout, N);
    k_attn<<<gAttn, b256, 0, stream>>>((const u16*)buf1, fout, att2, cnt, csrc, b2,
                                       fout, N, NP, 0);
}

// Round 12
// 206.247 us; speedup vs baseline: 6.2750x; 6.2750x over previous
//
#include <hip/hip_runtime.h>
#include <math.h>

#define NEG_SLOPE 0.2f
#define EPSV 1e-16f
#define NEG_HUGE -1e30f
#define CAP 64   // slots per node; deg ~ Poisson(16)+1, P(deg>63) ~ 1e-12
#define GH 768   // CSR builder blocks: 96 stripes x 8 XCD classes (R12: single-var TLP bump)

typedef short short8 __attribute__((ext_vector_type(8)));   // 8 bf16 (4 VGPRs)
typedef float f32x4 __attribute__((ext_vector_type(4)));
typedef unsigned short u16;

// cnt layout CLASS-MAJOR: cnt[(d&7)*NP + (d>>3)], NP padded to 32 ints.
// R3: no per-row matvec fusion (zero W-reuse). R6: no NT loads/stores.
// R7: hist not fetch-bound. R8: keep hist||gemm fused. R9: bf16 xl halves
// gather traffic (verified) but total flat -> attn latency-bound not BW.
// R10: 8-deep gather MLP flat -> attn not depth-bound either.
// R11: cooperative mega-kernel = 6x REGRESSION (FETCH 365MB: grid.sync
// forces cross-XCD L2 writeback-invalidate every phase; dispatch boundaries
// are CHEAPER than device-wide coherence). Dead end; 5-dispatch restored.
// R12: single variable vs R10 -- GH 512->768 (builder TLP x1.5 in the fused
// dispatch; R6's GH=1024 regression was confounded with NT+8-wide).

__device__ __forceinline__ u16 f2bf(float f) {            // RNE fp32->bf16
    const unsigned u = __float_as_uint(f);
    return (u16)((u + 0x7fffu + ((u >> 16) & 1u)) >> 16);
}
__device__ __forceinline__ float bf2f(u16 h) {
    return __uint_as_float(((unsigned)h) << 16);
}

// ---------------- W pre-pack + cnt/csrc prefill (one dispatch) --------------
__global__ __launch_bounds__(256) void k_wpack(
        const float* __restrict__ W1l, const float* __restrict__ W1r,
        const float* __restrict__ W2l, const float* __restrict__ W2r,
        u16* __restrict__ w1hi, u16* __restrict__ w1lo,
        u16* __restrict__ w2hi, u16* __restrict__ w2lo,
        int* __restrict__ cnt, u16* __restrict__ csrc, int N, int NP) {
    const int idx = blockIdx.x * 256 + threadIdx.x;
    const int G = gridDim.x * 256;
    const int CN = 8 * NP;
    // cnt init: 1 for valid d (self-loop pre-reserved in slot 0), 0 for pad
    for (int i = idx; i < CN; i += G) {
        const int cls = i / NP;
        const int r = i - cls * NP;
        const int d = r * 8 + cls;
        cnt[i] = (d < N) ? 1 : 0;
    }
    // self-loop prefill: slot 0 of every row
    for (int d = idx; d < N; d += G) csrc[(size_t)d * CAP] = (u16)d;
    const int T1 = 128 * 128, T2 = 64 * 128;
    if (idx >= T1 + T2) return;
    u16 *dhi, *dlo; const float *Wl, *Wr; int li;
    if (idx < T1) { dhi = w1hi; dlo = w1lo; Wl = W1l; Wr = W1r; li = idx; }
    else          { dhi = w2hi; dlo = w2lo; Wl = W2l; Wr = W2r; li = idx - T1; }
    const int j = li & 7, l = (li >> 3) & 63, t = (li >> 9) & 7, c = li >> 12;
    const int k = c * 32 + (l >> 4) * 8 + j;
    const int n = t * 16 + (l & 15);
    const float v = (n < 64) ? Wl[k * 64 + n] : Wr[k * 64 + (n - 64)];
    const unsigned u = __float_as_uint(v);
    dhi[li] = (u16)(u >> 16);
    const float hif = __uint_as_float(u & 0xffff0000u);
    dlo[li] = (u16)(__float_as_uint(v - hif) >> 16);
}

// ---------------- split fp32 x8 -> bf16 hi/lo -------------------------------
__device__ __forceinline__ void split8(const float* fs, short8& ahi, short8& alo) {
#pragma unroll
    for (int j = 0; j < 8; ++j) {
        const unsigned u = __float_as_uint(fs[j]);
        ahi[j] = (short)(u >> 16);
        const float hif = __uint_as_float(u & 0xffff0000u);
        alo[j] = (short)(__float_as_uint(fs[j] - hif) >> 16);
    }
}

// ---------------- split-bf16 MFMA GEMM tile (no LDS) ------------------------
// wave w computes rows [tile*64+w*16,+16) x 128 cols (Wl|Wr concat).
// Operands swapped: mfma(Wfrag, Xfrag) computes Y^T in fragment space ->
// lane l, reg r holds Y[rowbase+(l&15)][t*16+(l>>4)*4+r]: one vector store
// per tile (R2 win). xl (attn gather source) written bf16 (R9); xr fp32.
// D = Whi*Xhi + Wlo*Xhi + Whi*Xlo (lo*lo dropped, ~2^-16 rel).
template <int K>
__device__ __forceinline__ void gemm_mfma_tile(const float* __restrict__ X,
                                               const u16* __restrict__ whi,
                                               const u16* __restrict__ wlo,
                                               u16* __restrict__ xl,
                                               float* __restrict__ xr,
                                               int N, int tile) {
    const int lane = threadIdx.x & 63;
    const int w = threadIdx.x >> 6;
    const int rowbase = tile * 64 + w * 16;
    const int m = lane & 15, q = lane >> 4;
    int ar = rowbase + m; if (ar > N - 1) ar = N - 1;       // clamped read, masked write
    const float* arow = X + (size_t)ar * K + q * 8;
    f32x4 acc[8];
#pragma unroll
    for (int t = 0; t < 8; ++t) acc[t] = (f32x4){0.f, 0.f, 0.f, 0.f};
#pragma unroll
    for (int c = 0; c < K / 32; ++c) {
        const float4 f0 = *(const float4*)(arow + c * 32);
        const float4 f1 = *(const float4*)(arow + c * 32 + 4);
        const float fs[8] = {f0.x, f0.y, f0.z, f0.w, f1.x, f1.y, f1.z, f1.w};
        short8 ahi, alo;
        split8(fs, ahi, alo);
        const u16* bp = whi + ((size_t)(c * 8) * 64 + lane) * 8;
        const u16* bq = wlo + ((size_t)(c * 8) * 64 + lane) * 8;
#pragma unroll
        for (int t = 0; t < 8; ++t) {
            const short8 bhi = *(const short8*)(bp + t * 64 * 8);
            const short8 blo = *(const short8*)(bq + t * 64 * 8);
            acc[t] = __builtin_amdgcn_mfma_f32_16x16x32_bf16(bhi, ahi, acc[t], 0, 0, 0);
            acc[t] = __builtin_amdgcn_mfma_f32_16x16x32_bf16(blo, ahi, acc[t], 0, 0, 0);
            acc[t] = __builtin_amdgcn_mfma_f32_16x16x32_bf16(bhi, alo, acc[t], 0, 0, 0);
        }
    }
    const int row = rowbase + m;
    if (row < N) {
#pragma unroll
        for (int t = 0; t < 8; ++t) {
            const int colb = t * 16 + q * 4;
            if (t < 4) {
                ushort4 hv;
                hv.x = f2bf(acc[t][0]); hv.y = f2bf(acc[t][1]);
                hv.z = f2bf(acc[t][2]); hv.w = f2bf(acc[t][3]);
                *(ushort4*)(xl + (size_t)row * 64 + colb) = hv;   // 8B store
            } else {
                float4 v;
                v.x = acc[t][0]; v.y = acc[t][1]; v.z = acc[t][2]; v.w = acc[t][3];
                *(float4*)(xr + (size_t)row * 64 + (colb - 64)) = v;
            }
        }
    }
}

// ---------------- CSR build (XCD-class partitioned) || layer-1 gemm ---------
template <int K>
__global__ __launch_bounds__(256) void k_hist_gemm(const int* __restrict__ ei, int E,
                                                   int* __restrict__ cnt,
                                                   u16* __restrict__ csrc,
                                                   const float* __restrict__ X,
                                                   const u16* __restrict__ whi,
                                                   const u16* __restrict__ wlo,
                                                   u16* __restrict__ xl,
                                                   float* __restrict__ xr,
                                                   int N, int NP) {
    if ((int)blockIdx.x < GH) {
        const int cls = blockIdx.x & 7;
        const int stripe = blockIdx.x >> 3;      // 0..GH/8-1
        const int NS = GH >> 3;                  // stripes
        const int tid = threadIdx.x;
        const int* srcp = ei;
        const int* dstp = ei + E;
        int* cntc = cnt + cls * NP;
        if ((E & 3) == 0) {
            for (int base = stripe * 1024; base < E; base += NS * 1024) {
                const int e4 = base + tid * 4;
                if (e4 < E) {   // E%4==0 -> e4+3 <= E-1
                    const int4 d4 = *(const int4*)(dstp + e4);
                    const int4 s4 = *(const int4*)(srcp + e4);
                    const int d[4] = {d4.x, d4.y, d4.z, d4.w};
                    const int s[4] = {s4.x, s4.y, s4.z, s4.w};
                    bool m[4]; int sl[4];
#pragma unroll
                    for (int j = 0; j < 4; ++j) {
                        m[j] = (d[j] & 7) == cls;
                        if (m[j]) sl[j] = atomicAdd(&cntc[d[j] >> 3], 1);
                    }
#pragma unroll
                    for (int j = 0; j < 4; ++j) {
                        if (m[j]) csrc[(size_t)d[j] * CAP + sl[j]] = (u16)s[j];
                    }
                }
            }
        } else {
            for (int base = stripe * 256; base < E; base += NS * 256) {
                const int e = base + tid;
                if (e < E) {
                    const int dd = dstp[e];
                    if ((dd & 7) == cls) {
                        const int ss = srcp[e];
                        const int slot = atomicAdd(&cntc[dd >> 3], 1);
                        csrc[(size_t)dd * CAP + slot] = (u16)ss;
                    }
                }
            }
        }
    } else {
        gemm_mfma_tile<K>(X, whi, wlo, xl, xr, N, blockIdx.x - GH);
    }
}

template <int K>
__global__ __launch_bounds__(256) void k_gemm(const float* __restrict__ X,
                                              const u16* __restrict__ whi,
                                              const u16* __restrict__ wlo,
                                              u16* __restrict__ xl,
                                              float* __restrict__ xr, int N) {
    gemm_mfma_tile<K>(X, whi, wlo, xl, xr, N, blockIdx.x);
}

// ---------------- attn core: NT*16 edge slots, ALL gathers issued first -----
// All indices compile-time (runtime-indexed ext-vector arrays -> scratch).
template <int NT>
__device__ __forceinline__ void attn_core(const u16* __restrict__ xl,
                                          int sidx, int deg, int base,
                                          int g, int i,
                                          const float4 xrv, const float4 aw,
                                          float& l, float4& acc) {
    ushort4 u[NT][4];
    bool vv[NT][4];
#pragma unroll
    for (int nt = 0; nt < NT; ++nt) {
#pragma unroll
        for (int j = 0; j < 4; ++j) {
            const int s = base + nt * 16 + j * 4 + g;
            vv[nt][j] = s < deg;
            const int src = __shfl(sidx, s, 64);
            u[nt][j] = *(const ushort4*)(xl + (size_t)src * 64 + i * 4);
        }
    }
#pragma unroll
    for (int nt = 0; nt < NT; ++nt) {
#pragma unroll
        for (int j = 0; j < 4; ++j) {
            float4 va;
            va.x = bf2f(u[nt][j].x); va.y = bf2f(u[nt][j].y);
            va.z = bf2f(u[nt][j].z); va.w = bf2f(u[nt][j].w);
            float t0, pp;
            t0 = va.x + xrv.x; t0 = fmaxf(t0, NEG_SLOPE * t0); pp = aw.x * t0;
            t0 = va.y + xrv.y; t0 = fmaxf(t0, NEG_SLOPE * t0); pp = fmaf(aw.y, t0, pp);
            t0 = va.z + xrv.z; t0 = fmaxf(t0, NEG_SLOPE * t0); pp = fmaf(aw.z, t0, pp);
            t0 = va.w + xrv.w; t0 = fmaxf(t0, NEG_SLOPE * t0); pp = fmaf(aw.w, t0, pp);
            pp += __shfl_xor(pp, 1, 64);
            pp += __shfl_xor(pp, 2, 64);
            pp += __shfl_xor(pp, 4, 64);
            pp += __shfl_xor(pp, 8, 64);
            const float dj = __expf(vv[nt][j] ? pp : NEG_HUGE);
            l += dj;
            acc.x = fmaf(dj, va.x, acc.x);
            acc.y = fmaf(dj, va.y, acc.y);
            acc.z = fmaf(dj, va.z, acc.z);
            acc.w = fmaf(dj, va.w, acc.w);
        }
    }
}

// ---------------- fused attention (one wave per dst) ------------------------
// deg is wave-uniform -> uniform branch, no divergence. xr/out not
// __restrict__: layer 2 aliases both to d_out (per-wave row read-then-write).
__global__ __launch_bounds__(256) void k_attn(const u16* __restrict__ xl,
                                              const float* xr,
                                              const float* __restrict__ att,
                                              const int* __restrict__ cnt,
                                              const u16* __restrict__ csrc,
                                              const float* __restrict__ bias,
                                              float* out, int N, int NP, int relu) {
    const int lane = threadIdx.x & 63;
    const int g = lane >> 4;
    const int i = lane & 15;
    const int dst = blockIdx.x * 4 + (threadIdx.x >> 6);
    if (dst >= N) return;
    const float4 xrv = *(const float4*)(xr + (size_t)dst * 64 + i * 4);
    const float4 aw  = *(const float4*)(att + i * 4);
    const int deg = cnt[(dst & 7) * NP + (dst >> 3)];
    const int sidx = (int)csrc[(size_t)dst * CAP + ((lane < deg) ? lane : 0)];
    float l = 0.0f;
    float4 acc = {0.0f, 0.0f, 0.0f, 0.0f};
    if (deg <= 16) {
        attn_core<1>(xl, sidx, deg, 0, g, i, xrv, aw, l, acc);
    } else if (deg <= 32) {
        attn_core<2>(xl, sidx, deg, 0, g, i, xrv, aw, l, acc);
    } else {          // 0.03% of waves
        attn_core<2>(xl, sidx, deg, 0, g, i, xrv, aw, l, acc);
        attn_core<2>(xl, sidx, deg, 32, g, i, xrv, aw, l, acc);
    }
    // merge the 4 groups (plain sums)
#pragma unroll
    for (int o = 16; o <= 32; o <<= 1) {
        l     += __shfl_xor(l, o, 64);
        acc.x += __shfl_xor(acc.x, o, 64);
        acc.y += __shfl_xor(acc.y, o, 64);
        acc.z += __shfl_xor(acc.z, o, 64);
        acc.w += __shfl_xor(acc.w, o, 64);
    }
    if (g == 0) {
        const float4 bv = *(const float4*)(bias + i * 4);
        const float inv = 1.0f / (l + EPSV);
        float4 r;
        r.x = fmaf(acc.x, inv, bv.x);
        r.y = fmaf(acc.y, inv, bv.y);
        r.z = fmaf(acc.z, inv, bv.z);
        r.w = fmaf(acc.w, inv, bv.w);
        if (relu) {
            r.x = fmaxf(r.x, 0.0f); r.y = fmaxf(r.y, 0.0f);
            r.z = fmaxf(r.z, 0.0f); r.w = fmaxf(r.w, 0.0f);
        }
        *(float4*)(out + (size_t)dst * 64 + i * 4) = r;
    }
}

// ---------------- launch ----------------

extern "C" void kernel_launch(void* const* d_in, const int* in_sizes, int n_in,
                              void* d_out, int out_size, void* d_ws, size_t ws_size,
                              hipStream_t stream) {
    const float* x    = (const float*)d_in[0];
    const int*   ei   = (const int*)d_in[1];
    const float* W1l  = (const float*)d_in[2];
    const float* W1r  = (const float*)d_in[3];
    const float* att1 = (const float*)d_in[4];
    const float* b1   = (const float*)d_in[5];
    const float* W2l  = (const float*)d_in[6];
    const float* W2r  = (const float*)d_in[7];
    const float* att2 = (const float*)d_in[8];
    const float* b2   = (const float*)d_in[9];

    const int N  = in_sizes[0] / 128;
    const int E  = in_sizes[1] / 2;
    const int NP = (((N + 7) >> 3) + 31) & ~31;   // per-class cnt stride, 128B-aligned

    // ws: cnt(8*NP) | csrc(u16) | W packs | buf1 | buf2
    int* wsi   = (int*)d_ws;
    int* cnt   = wsi;                        // 8*NP ints (class-major)
    u16* csrc  = (u16*)(cnt + 8 * NP);       // N*CAP u16
    u16* w1hi  = csrc + (size_t)N * CAP;
    u16* w1lo  = w1hi + 16384;
    u16* w2hi  = w1lo + 16384;
    u16* w2lo  = w2hi + 8192;
    float* buf1 = (float*)(w2lo + 8192);     // N*64 f32 (xr1), then N*64 bf16 (xl2)
    float* buf2 = buf1 + (size_t)N * 64;     // N*64 f32 (h)
    float* fout = (float*)d_out;             // xl1 (bf16 region), xr2, final out

    const dim3 b256(256);
    const int gGemm = (N + 63) / 64;
    const int gAttn = (N + 3) / 4;

    // ---- W pack + cnt/csrc prefill ----
    k_wpack<<<96, b256, 0, stream>>>(
        W1l, W1r, W2l, W2r, w1hi, w1lo, w2hi, w2lo, cnt, csrc, N, NP);

    // ---- XCD-partitioned CSR build || layer-1 gemm (xl1 bf16 -> d_out, xr1 -> buf1) ----
    k_hist_gemm<128><<<GH + gGemm, b256, 0, stream>>>(ei, E, cnt, csrc,
                                                      x, w1hi, w1lo,
                                                      (u16*)fout, buf1, N, NP);
    // ---- Layer 1 attention: gathers bf16 xl1, h(f32) -> buf2 ----
    k_attn<<<gAttn, b256, 0, stream>>>((const u16*)fout, buf1, att1, cnt, csrc, b1,
                                       buf2, N, NP, 1);

    // ---- Layer 2 gemm: reads h(buf2), xl2 bf16 -> buf1, xr2 f32 -> d_out ----
    k_gemm<64><<<gGemm, b256, 0, stream>>>(buf2, w2hi, w2lo, (u16*)buf1, fout, N);
    // attn2 gathers bf16 xl2 from buf1, reads xr from d_out, overwrites d_out per-row
    k_attn<<<gAttn, b256, 0, stream>>>((const u16*)buf1, fout, att2, cnt, csrc, b2,
                                       fout, N, NP, 0);
}